// Round 1
// baseline (2645.549 us; speedup 1.0000x reference)
//
#include <hip/hip_runtime.h>
#include <hip/hip_bf16.h>
#include <cstdint>

// Problem constants (Experts FFN): W=8, E=4, C=2048, H=1024, DFF=4096
#define W_   8
#define E_   4
#define C_   2048
#define H_   1024
#define DFF_ 4096

typedef unsigned short u16;
typedef __attribute__((ext_vector_type(8))) short bf16x8;   // 8 bf16 = 4 VGPRs
typedef __attribute__((ext_vector_type(4))) float f32x4;    // MFMA 16x16 accumulator

// ---------- helpers ----------
__device__ __forceinline__ u16 f2bf(float f) {
  union { float f; uint32_t u; } v; v.f = f;
  uint32_t u = v.u;
  uint32_t r = (u + 0x7FFFu + ((u >> 16) & 1u)) >> 16;  // RNE
  return (u16)r;
}

// async global->LDS, 16B per lane; LDS dest = wave-uniform base + lane*16
__device__ __forceinline__ void async_cp16(const u16* g, u16* l) {
  __builtin_amdgcn_global_load_lds(
      (__attribute__((address_space(1))) void*)(g),
      (__attribute__((address_space(3))) void*)(l),
      16, 0, 0);
}

// ---------- conversion kernels ----------
__global__ __launch_bounds__(256) void cvt_x_kernel(const float* __restrict__ in,
                                                    u16* __restrict__ out, long n) {
  long i = ((long)blockIdx.x * 256 + threadIdx.x) * 4;
  if (i < n) {
    float4 v = *(const float4*)&in[i];
    ushort4 o;
    o.x = f2bf(v.x); o.y = f2bf(v.y); o.z = f2bf(v.z); o.w = f2bf(v.w);
    *(ushort4*)&out[i] = o;
  }
}

// in: fp32 [E][R][Cn]  ->  out: bf16 [E][Cn][R]   (B^T layout for gemm_bt)
__global__ __launch_bounds__(256) void transpose_cvt_kernel(const float* __restrict__ in,
                                                            u16* __restrict__ out,
                                                            int R, int Cn) {
  __shared__ u16 tile[32][33];
  const int e  = blockIdx.z;
  const int c0 = blockIdx.x * 32;
  const int r0 = blockIdx.y * 32;
  const float* inp = in + (size_t)e * R * Cn;
  u16* outp = out + (size_t)e * R * Cn;
  const int tx = threadIdx.x;   // 0..31
  const int ty = threadIdx.y;   // 0..7
#pragma unroll
  for (int j = ty; j < 32; j += 8)
    tile[j][tx] = f2bf(inp[(size_t)(r0 + j) * Cn + (c0 + tx)]);
  __syncthreads();
#pragma unroll
  for (int j = ty; j < 32; j += 8)
    outp[(size_t)(c0 + j) * R + (r0 + tx)] = tile[tx][j];
}

// ---------- GEMM core: C[M,N] = A[M,K] * Bt[N,K]^T (+bias, opt GELU) ----------
// 128x128 tile, BK=32, 256 threads (4 waves, 2x2), 4x4 mfma_f32_16x16x32_bf16/wave.
// LDS tiles in chunked layout [kb=0..3][row=0..127][8 bf16] (16B chunks).
template<bool GELU>
__device__ __forceinline__ void gemm_core(const u16* __restrict__ A,
                                          const u16* __restrict__ B,
                                          const float* __restrict__ bias,
                                          void* __restrict__ Cout,
                                          int K, int N) {
  __shared__ alignas(16) u16 As[4 * 128 * 8];
  __shared__ alignas(16) u16 Bs[4 * 128 * 8];

  const int tid  = threadIdx.x;
  const int wid  = tid >> 6;
  const int lane = tid & 63;
  const int wm   = wid >> 1;      // wave row 0..1
  const int wn   = wid & 1;       // wave col 0..1
  const int q    = lane >> 4;     // quad 0..3
  const int l15  = lane & 15;

  const int rowBase = blockIdx.y * 128;
  const int colBase = blockIdx.x * 128;

  f32x4 acc[4][4] = {};

  // staging: wave `wid` owns k-chunk plane kb=wid for both A and B
  const u16* ga0 = A + (size_t)(rowBase + lane) * K + wid * 8;
  const u16* ga1 = ga0 + (size_t)64 * K;
  const u16* gb0 = B + (size_t)(colBase + lane) * K + wid * 8;
  const u16* gb1 = gb0 + (size_t)64 * K;
  u16* la0 = &As[(wid * 128 +  0) * 8];
  u16* la1 = &As[(wid * 128 + 64) * 8];
  u16* lb0 = &Bs[(wid * 128 +  0) * 8];
  u16* lb1 = &Bs[(wid * 128 + 64) * 8];

  const int nk = K >> 5;
  for (int kt = 0; kt < nk; ++kt) {
    __syncthreads();
    async_cp16(ga0, la0);
    async_cp16(ga1, la1);
    async_cp16(gb0, lb0);
    async_cp16(gb1, lb1);
    ga0 += 32; ga1 += 32; gb0 += 32; gb1 += 32;
    __syncthreads();   // compiler drains vmcnt before barrier

    bf16x8 af[4], bfr[4];
#pragma unroll
    for (int mi = 0; mi < 4; ++mi)
      af[mi] = *(const bf16x8*)&As[((q * 128) + wm * 64 + mi * 16 + l15) * 8];
#pragma unroll
    for (int ni = 0; ni < 4; ++ni)
      bfr[ni] = *(const bf16x8*)&Bs[((q * 128) + wn * 64 + ni * 16 + l15) * 8];

#pragma unroll
    for (int mi = 0; mi < 4; ++mi)
#pragma unroll
      for (int ni = 0; ni < 4; ++ni)
        acc[mi][ni] = __builtin_amdgcn_mfma_f32_16x16x32_bf16(af[mi], bfr[ni],
                                                              acc[mi][ni], 0, 0, 0);
  }

  // epilogue — C/D layout: col = lane&15, row = quad*4 + reg (m89/m91-verified)
  float bv[4];
#pragma unroll
  for (int ni = 0; ni < 4; ++ni)
    bv[ni] = bias[colBase + wn * 64 + ni * 16 + l15];

#pragma unroll
  for (int mi = 0; mi < 4; ++mi) {
#pragma unroll
    for (int ni = 0; ni < 4; ++ni) {
      const int col = colBase + wn * 64 + ni * 16 + l15;
#pragma unroll
      for (int i = 0; i < 4; ++i) {
        const int row = rowBase + wm * 64 + mi * 16 + q * 4 + i;
        float x = acc[mi][ni][i] + bv[ni];
        if (GELU) {
          // jax.nn.gelu default (approximate=True, tanh form)
          const float t  = 0.7978845608028654f * (x + 0.044715f * x * x * x);
          const float e  = __expf(2.0f * t);
          const float th = 1.0f - 2.0f / (e + 1.0f);
          const float y  = 0.5f * x * (1.0f + th);
          ((u16*)Cout)[(size_t)row * N + col] = f2bf(y);
        } else {
          ((float*)Cout)[(size_t)row * N + col] = x;
        }
      }
    }
  }
}

// groups g = (w_local * E + e);  e = g & 3
__global__ __launch_bounds__(256) void gemm1_kernel(const u16* __restrict__ Xb,
                                                    const u16* __restrict__ W1t,
                                                    const float* __restrict__ b1,
                                                    u16* __restrict__ Hb) {
  const int g = blockIdx.z;
  const int e = g & 3;
  gemm_core<true>(Xb + (size_t)g * C_ * H_,
                  W1t + (size_t)e * DFF_ * H_,
                  b1  + (size_t)e * DFF_,
                  Hb  + (size_t)g * C_ * DFF_,
                  H_, DFF_);
}

__global__ __launch_bounds__(256) void gemm2_kernel(const u16* __restrict__ Hb,
                                                    const u16* __restrict__ W2t,
                                                    const float* __restrict__ b2,
                                                    float* __restrict__ Out) {
  const int g = blockIdx.z;
  const int e = g & 3;
  gemm_core<false>(Hb  + (size_t)g * C_ * DFF_,
                   W2t + (size_t)e * H_ * DFF_,
                   b2  + (size_t)e * H_,
                   Out + (size_t)g * C_ * H_,
                   DFF_, H_);
}

// ---------- launch ----------
extern "C" void kernel_launch(void* const* d_in, const int* in_sizes, int n_in,
                              void* d_out, int out_size, void* d_ws, size_t ws_size,
                              hipStream_t stream) {
  const float* X  = (const float*)d_in[0];
  const float* W1 = (const float*)d_in[1];
  const float* b1 = (const float*)d_in[2];
  const float* W2 = (const float*)d_in[3];
  const float* b2 = (const float*)d_in[4];
  float* out = (float*)d_out;

  char* ws = (char*)d_ws;
  const size_t xb_elems = (size_t)W_ * E_ * C_ * H_;   // 64M
  const size_t w_elems  = (size_t)E_ * H_ * DFF_;      // 16M
  size_t off = 0;
  auto take = [&](size_t bytes) {
    size_t o = off; off += (bytes + 255) & ~(size_t)255; return o;
  };
  const size_t off_x  = take(xb_elems * 2);   // 128 MB
  const size_t off_w1 = take(w_elems * 2);    //  32 MB
  const size_t off_w2 = take(w_elems * 2);    //  32 MB
  u16* Xb  = (u16*)(ws + off_x);
  u16* W1t = (u16*)(ws + off_w1);
  u16* W2t = (u16*)(ws + off_w2);

  const size_t h_per_w = (size_t)E_ * C_ * DFF_ * 2;   // 64 MB per w-slice
  const size_t avail = ws_size > off ? ws_size - off : 0;
  int Wp;                                              // w-slices per pass
  if      (avail >= 8 * h_per_w) Wp = 8;
  else if (avail >= 4 * h_per_w) Wp = 4;
  else if (avail >= 2 * h_per_w) Wp = 2;
  else                           Wp = 1;               // best effort
  u16* Hb = (u16*)(ws + off);

  // one-time conversions (serialized on stream before the GEMM passes)
  cvt_x_kernel<<<dim3((unsigned)(xb_elems / 4 / 256)), dim3(256), 0, stream>>>(
      X, Xb, (long)xb_elems);
  transpose_cvt_kernel<<<dim3(DFF_ / 32, H_ / 32, E_), dim3(32, 8), 0, stream>>>(
      W1, W1t, H_, DFF_);
  transpose_cvt_kernel<<<dim3(H_ / 32, DFF_ / 32, E_), dim3(32, 8), 0, stream>>>(
      W2, W2t, DFF_, H_);

  for (int w0 = 0; w0 < W_; w0 += Wp) {
    const int groups = Wp * E_;
    gemm1_kernel<<<dim3(DFF_ / 128, C_ / 128, groups), dim3(256), 0, stream>>>(
        Xb + (size_t)w0 * E_ * C_ * H_, W1t, b1, Hb);
    gemm2_kernel<<<dim3(H_ / 128, C_ / 128, groups), dim3(256), 0, stream>>>(
        Hb, W2t, b2, out + (size_t)w0 * E_ * C_ * H_);
  }
}